// Round 1
// baseline (199.703 us; speedup 1.0000x reference)
//
#include <hip/hip_runtime.h>

// Reduction: mean(|convdata[:,:,3] - output[:,:,3]|)
// B=64, S=100, K=4, H=W=32. Channel-3 slice per (b,s) pair is a contiguous
// 1024-float (4 KB) chunk at float offset (pair*4 + 3)*1024.
// Total reduced elements: 64*100*1024 = 6,553,600  (52.4 MB read total).
//
// Single fused kernel: grid-stride float4 loads -> wave shuffle reduce ->
// LDS cross-wave reduce -> one device-scope atomicAdd per block.
// d_out is zeroed with a 4-byte hipMemsetAsync (graph-capturable).
//
// grid = 2048 blocks * 256 thr = 8192 waves = 256 CU * 32 wave slots (full).

#define RBLOCKS 2048
#define RTHREADS 256

__global__ __launch_bounds__(RTHREADS)
void absdiff_reduce_kernel(const float4* __restrict__ outp,
                           const float4* __restrict__ conv,
                           float* __restrict__ out,
                           int n4, float inv_total) {
    // Two independent accumulators to break the dependent-add chain
    // across grid-stride iterations (~3 iters/thread at this grid).
    float acc0 = 0.0f, acc1 = 0.0f;
    const int stride  = gridDim.x * blockDim.x;
    const int stride2 = stride * 2;
    int v = blockIdx.x * blockDim.x + threadIdx.x;

    for (; v + stride < n4; v += stride2) {
        // v indexes float4s within the channel-3 subspace.
        // pair = v / 256 (256 float4 per 4 KB chunk); chunk lives at
        // float4 offset pair*1024 + 768 in the full [.,.,4,32,32] array.
        {
            const int pair = v >> 8;
            const size_t g = (size_t)pair * 1024 + 768 + (size_t)(v & 255);
            const float4 a = outp[g];
            const float4 b = conv[g];
            acc0 += fabsf(b.x - a.x) + fabsf(b.y - a.y)
                  + fabsf(b.z - a.z) + fabsf(b.w - a.w);
        }
        {
            const int v1 = v + stride;
            const int pair = v1 >> 8;
            const size_t g = (size_t)pair * 1024 + 768 + (size_t)(v1 & 255);
            const float4 a = outp[g];
            const float4 b = conv[g];
            acc1 += fabsf(b.x - a.x) + fabsf(b.y - a.y)
                  + fabsf(b.z - a.z) + fabsf(b.w - a.w);
        }
    }
    if (v < n4) {
        const int pair = v >> 8;
        const size_t g = (size_t)pair * 1024 + 768 + (size_t)(v & 255);
        const float4 a = outp[g];
        const float4 b = conv[g];
        acc0 += fabsf(b.x - a.x) + fabsf(b.y - a.y)
              + fabsf(b.z - a.z) + fabsf(b.w - a.w);
    }
    float acc = acc0 + acc1;

    // wave-64 shuffle reduction
    #pragma unroll
    for (int off = 32; off > 0; off >>= 1)
        acc += __shfl_down(acc, off, 64);

    __shared__ float smem[RTHREADS / 64];
    const int lane = threadIdx.x & 63;
    const int wave = threadIdx.x >> 6;
    if (lane == 0) smem[wave] = acc;
    __syncthreads();
    if (threadIdx.x == 0) {
        float s = 0.0f;
        #pragma unroll
        for (int w = 0; w < RTHREADS / 64; ++w) s += smem[w];
        // One device-scope atomic per block (2048 total) — negligible
        // contention; fp-order nondeterminism ~2^-23 relative.
        atomicAdd(out, s * inv_total);
    }
}

extern "C" void kernel_launch(void* const* d_in, const int* in_sizes, int n_in,
                              void* d_out, int out_size, void* d_ws, size_t ws_size,
                              hipStream_t stream) {
    const float4* outp = (const float4*)d_in[0];   // "output"
    const float4* conv = (const float4*)d_in[1];   // "convdata"
    float* out = (float*)d_out;

    const int n_elems = 64 * 100 * 1024;           // 6,553,600
    const int n4 = n_elems / 4;                    // 1,638,400
    const float inv_total = 1.0f / (float)n_elems;

    hipMemsetAsync(out, 0, sizeof(float), stream);
    absdiff_reduce_kernel<<<RBLOCKS, RTHREADS, 0, stream>>>(outp, conv, out,
                                                            n4, inv_total);
}

// Round 3
// 179.510 us; speedup vs baseline: 1.1125x; 1.1125x over previous
//
#include <hip/hip_runtime.h>

// Reduction: mean(|convdata[:,:,3] - output[:,:,3]|)
// B=64, S=100, K=4, H=W=32. Channel-3 slice per (b,s) pair is a contiguous
// 1024-float (4 KB) chunk at float offset (pair*4 + 3)*1024.
// Total reduced: 64*100*1024 = 6,553,600 elems (52.4 MB read).
//
// Round-1 structure: NO memset/fillBuffer node (they cost ~20-60us as graph
// nodes in this harness). Two dispatches:
//   1) partial kernel: 2048 blocks (full 8192-wave occupancy), each block
//      owns whole 4KB chunks (256 float4 = 256 threads, 1:1), writes one
//      partial per block to d_ws.
//   2) final kernel: 1 block reduces 2048 partials, OVERWRITES out[0]
//      (no zero-init needed anywhere).

#define RBLOCKS 2048
#define RTHREADS 256
#define NCHUNKS 6400   // 64*100 (b,s) pairs, one 4KB channel-3 chunk each

__global__ __launch_bounds__(RTHREADS)
void absdiff_partial_kernel(const float4* __restrict__ outp,
                            const float4* __restrict__ conv,
                            float* __restrict__ partials) {
    const int t = threadIdx.x;
    float acc0 = 0.0f, acc1 = 0.0f;

    // Block b handles chunks b, b+2048, b+4096, (b+6144 if b<256).
    // Chunk c's channel-3 data: float4 index c*1024 + 768 + t.
    int c = blockIdx.x;
    for (; c + RBLOCKS < NCHUNKS; c += 2 * RBLOCKS) {
        const size_t g0 = (size_t)c * 1024 + 768 + t;
        const size_t g1 = (size_t)(c + RBLOCKS) * 1024 + 768 + t;
        const float4 a0 = outp[g0];
        const float4 b0 = conv[g0];
        const float4 a1 = outp[g1];
        const float4 b1 = conv[g1];
        acc0 += fabsf(b0.x - a0.x) + fabsf(b0.y - a0.y)
              + fabsf(b0.z - a0.z) + fabsf(b0.w - a0.w);
        acc1 += fabsf(b1.x - a1.x) + fabsf(b1.y - a1.y)
              + fabsf(b1.z - a1.z) + fabsf(b1.w - a1.w);
    }
    if (c < NCHUNKS) {
        const size_t g = (size_t)c * 1024 + 768 + t;
        const float4 a = outp[g];
        const float4 b = conv[g];
        acc0 += fabsf(b.x - a.x) + fabsf(b.y - a.y)
              + fabsf(b.z - a.z) + fabsf(b.w - a.w);
    }
    float acc = acc0 + acc1;

    // wave-64 shuffle reduction
    #pragma unroll
    for (int off = 32; off > 0; off >>= 1)
        acc += __shfl_down(acc, off, 64);

    __shared__ float smem[RTHREADS / 64];
    const int lane = t & 63;
    const int wave = t >> 6;
    if (lane == 0) smem[wave] = acc;
    __syncthreads();
    if (t == 0) {
        float s = 0.0f;
        #pragma unroll
        for (int w = 0; w < RTHREADS / 64; ++w) s += smem[w];
        partials[blockIdx.x] = s;
    }
}

__global__ __launch_bounds__(RTHREADS)
void final_reduce_kernel(const float* __restrict__ partials,
                         float* __restrict__ out, float inv_total) {
    float acc = 0.0f;
    // 2048 partials / 256 threads = 8 each, fully unrolled.
    #pragma unroll
    for (int i = 0; i < RBLOCKS / RTHREADS; ++i)
        acc += partials[threadIdx.x + i * RTHREADS];
    #pragma unroll
    for (int off = 32; off > 0; off >>= 1)
        acc += __shfl_down(acc, off, 64);
    __shared__ float smem[RTHREADS / 64];
    const int lane = threadIdx.x & 63;
    const int wave = threadIdx.x >> 6;
    if (lane == 0) smem[wave] = acc;
    __syncthreads();
    if (threadIdx.x == 0) {
        float s = 0.0f;
        #pragma unroll
        for (int w = 0; w < RTHREADS / 64; ++w) s += smem[w];
        out[0] = s * inv_total;   // overwrite — no zero-init needed
    }
}

extern "C" void kernel_launch(void* const* d_in, const int* in_sizes, int n_in,
                              void* d_out, int out_size, void* d_ws, size_t ws_size,
                              hipStream_t stream) {
    const float4* outp = (const float4*)d_in[0];   // "output"
    const float4* conv = (const float4*)d_in[1];   // "convdata"
    float* partials = (float*)d_ws;                // RBLOCKS floats (8 KB)
    float* out = (float*)d_out;

    const float inv_total = 1.0f / (float)(64 * 100 * 1024);

    absdiff_partial_kernel<<<RBLOCKS, RTHREADS, 0, stream>>>(outp, conv, partials);
    final_reduce_kernel<<<1, RTHREADS, 0, stream>>>(partials, out, inv_total);
}